// Round 21
// baseline (52.402 us; speedup 1.0000x reference)
//
#include <hip/hip_runtime.h>
#include <math.h>

// B=4, T=2048, C=768, H=64
#define TB 2048
#define CB 768
#define NB 4
#define NROWS (NB * TB) // 8192
#define NSMAX 16        // max 128-wide KV splits per row
#define WGPB 136        // per-batch attn WGs: sum_{g=0..15} (g+1)

typedef __attribute__((ext_vector_type(8))) short bf16x8;
typedef __attribute__((ext_vector_type(4))) float f32x4;
typedef __attribute__((ext_vector_type(2))) float f32x2;
typedef __attribute__((ext_vector_type(2))) unsigned int u32x2;
typedef __attribute__((ext_vector_type(4))) unsigned int u32x4;

__device__ inline unsigned short f2bf(float f) {
  union { float f; unsigned u; } v; v.f = f;
  unsigned r = v.u + 0x7FFFu + ((v.u >> 16) & 1u);
  return (unsigned short)(r >> 16);
}
__device__ inline unsigned pack2bf(float a, float b) {
  return (unsigned)f2bf(a) | ((unsigned)f2bf(b) << 16);
}
__device__ inline float bf2f(unsigned short u) {
  union { unsigned u; float f; } v; v.u = (unsigned)u << 16; return v.f;
}

// ---------------- kernel 0: weights fp32 [C][64] x3 -> Wt bf16 [192][768] ----
__global__ void cvt_w_kernel(const float* __restrict__ Wq, const float* __restrict__ Wk,
                             const float* __restrict__ Wv, unsigned short* __restrict__ Wt) {
  __shared__ float tw[64][65];
  const float* W = (blockIdx.y == 0) ? Wq : (blockIdx.y == 1) ? Wk : Wv;
  const int c0 = blockIdx.x * 64;
  const int row = threadIdx.x >> 2, seg = threadIdx.x & 3;
#pragma unroll
  for (int i = 0; i < 4; ++i) {
    float4 f = *(const float4*)(W + (size_t)(c0 + row) * 64 + seg * 16 + i * 4);
    tw[row][seg * 16 + i * 4 + 0] = f.x;
    tw[row][seg * 16 + i * 4 + 1] = f.y;
    tw[row][seg * 16 + i * 4 + 2] = f.z;
    tw[row][seg * 16 + i * 4 + 3] = f.w;
  }
  __syncthreads();
  const int j = threadIdx.x >> 2, cq = threadIdx.x & 3;
  unsigned short* dst = Wt + (size_t)(blockIdx.y * 64 + j) * CB + c0 + cq * 16;
  u32x4 ua, ub;
#pragma unroll
  for (int i = 0; i < 4; ++i) ua[i] = pack2bf(tw[cq * 16 + 2 * i][j], tw[cq * 16 + 2 * i + 1][j]);
#pragma unroll
  for (int i = 0; i < 4; ++i) ub[i] = pack2bf(tw[cq * 16 + 8 + 2 * i][j], tw[cq * 16 + 9 + 2 * i][j]);
  *(u32x4*)dst = ua;
  *(u32x4*)(dst + 8) = ub;
}

// ---------------- kernel 1: QKV projection, FULL-K, 32-row M-tiles, 8 waves --
// grid 256, block 512. Wave wid: rows [m0+16*(wid>>2), +16), cols [(wid&3)*48, +48).
// Waves 0-3 and 4-7 share the same weight slices -> weight L2 traffic halved.
__launch_bounds__(512)
__global__ void proj_direct_kernel(const float* __restrict__ x,
                                   const unsigned short* __restrict__ Wt,
                                   unsigned short* __restrict__ q,
                                   unsigned short* __restrict__ k,
                                   unsigned short* __restrict__ vT) {
  __shared__ __align__(16) unsigned short xs[32 * 64]; // 32 rows x 64 k, swizzled
  __shared__ float tr[64][33];                         // v transpose staging
  const int tid = threadIdx.x;
  const int wid = tid >> 6;
  const int l = tid & 63;
  const int lrow = l & 15, lg = l >> 4;
  const int rh = (wid >> 2) * 16;       // row-half base within tile
  const int cw = (wid & 3) * 48;        // col base
  const int m0 = blockIdx.x * 32;
  const int srow = tid >> 4;            // staging row 0..31
  const int sq = tid & 15;              // 4-float segment
  const float* xp = x + (size_t)(m0 + srow) * CB + sq * 4;
  const int swz = (srow & 7) << 4;

  f32x4 acc[3];
#pragma unroll
  for (int n = 0; n < 3; ++n) acc[n] = (f32x4){0.f, 0.f, 0.f, 0.f};

  float4 f = *(const float4*)xp;
  for (int k0 = 0; k0 < CB; k0 += 64) {
    {
      u32x2 c;
      c.x = pack2bf(f.x, f.y);
      c.y = pack2bf(f.z, f.w);
      *(u32x2*)((char*)xs + srow * 128 + ((sq * 8) ^ swz)) = c;
    }
    if (k0 + 64 < CB) f = *(const float4*)(xp + k0 + 64);
    __syncthreads();

#pragma unroll
    for (int s = 0; s < 2; ++s) {
      int arow = rh + lrow; // (arow & 7) == (lrow & 7) since rh in {0,16}
      bf16x8 af = *(const bf16x8*)((const char*)xs + arow * 128 +
                                   ((s * 64 + lg * 16) ^ ((lrow & 7) << 4)));
#pragma unroll
      for (int nf = 0; nf < 3; ++nf) {
        int col = cw + nf * 16 + lrow;
        bf16x8 bfr = *(const bf16x8*)(Wt + (size_t)col * CB + k0 + s * 32 + lg * 8);
        acc[nf] = __builtin_amdgcn_mfma_f32_16x16x32_bf16(af, bfr, acc[nf], 0, 0, 0);
      }
    }
    __syncthreads();
  }

  // epilogue: D row (local) = rh + lg*4 + r, col j = cw + nf*16 + lrow
#pragma unroll
  for (int nf = 0; nf < 3; ++nf) {
    int j = cw + nf * 16 + lrow;
#pragma unroll
    for (int r = 0; r < 4; ++r) {
      int lrow2 = rh + lg * 4 + r;
      int grow = m0 + lrow2;
      if (j < 64)       q[(size_t)grow * 64 + j] = f2bf(acc[nf][r]);
      else if (j < 128) k[(size_t)grow * 64 + (j - 64)] = f2bf(acc[nf][r]);
      else              tr[j - 128][lrow2] = acc[nf][r];
    }
  }
  __syncthreads();
  // v writeout: 64 h-rows x 32 t, 8B per thread
  {
    const int b = m0 >> 11, t0 = m0 & (TB - 1);
    const int h = tid >> 3, tq = tid & 7;
    u32x2 pk;
    pk.x = pack2bf(tr[h][tq * 4 + 0], tr[h][tq * 4 + 1]);
    pk.y = pack2bf(tr[h][tq * 4 + 2], tr[h][tq * 4 + 3]);
    *(u32x2*)(vT + ((size_t)(b * 64 + h)) * TB + t0 + tq * 4) = pk;
  }
}

// ---------------- kernel 2: causal attention, 8 Q-tiles x 128-wide KV --------
// grid (WGPB, B), block 512 (8 waves). WG w -> (g, b128), b128 in [0, g].
__launch_bounds__(512)
__global__ void attn_kernel(const unsigned short* __restrict__ q,
                            const unsigned short* __restrict__ k,
                            const unsigned short* __restrict__ vT,
                            unsigned short* __restrict__ PO, float* __restrict__ Mp,
                            float* __restrict__ Lp) {
  __shared__ __align__(16) char ksm[2][8192]; // K sub-tiles, swz (r&7)<<4
  __shared__ __align__(16) char vsm[2][8192]; // V sub-tiles, swz (r&3)<<5
  const int tid = threadIdx.x;
  const int wid = tid >> 6, l = tid & 63;
  const int lrow = l & 15, lg = l >> 4;
  const int b = blockIdx.y;
  const int w = blockIdx.x;

  int g = (int)((sqrtf((float)(8 * w + 1)) - 1.f) * 0.5f);
  while ((g + 1) * (g + 2) / 2 <= w) ++g;
  while (g * (g + 1) / 2 > w) --g;
  const int b128 = w - g * (g + 1) / 2;
  const int kv0a = b128 * 128, kv0b = kv0a + 64;
  const int t = 8 * g + wid;
  const int q0w = t * 16;
  const int qrow = q0w + lrow;

  const unsigned short* qb = q + (size_t)b * TB * 64;
  const char* kbb = (const char*)(k + (size_t)b * TB * 64);
  const unsigned short* vb = vT + (size_t)b * 64 * TB;

  const int srow = tid >> 3;
  const int sc = (tid & 7) * 16;
  const int kswz_w = (srow & 7) << 4;
  const int vswz_w = (srow & 3) << 5;
  float4 ka = *(const float4*)(kbb + (size_t)kv0a * 128 + tid * 16);
  float4 kb2 = *(const float4*)(kbb + (size_t)kv0b * 128 + tid * 16);
  float4 va = *(const float4*)((const char*)(vb + (size_t)srow * TB + kv0a) + sc);
  float4 vb2 = *(const float4*)((const char*)(vb + (size_t)srow * TB + kv0b) + sc);

  bf16x8 qf[2];
#pragma unroll
  for (int s = 0; s < 2; ++s)
    qf[s] = *(const bf16x8*)(qb + (size_t)qrow * 64 + s * 32 + lg * 8);

  *(float4*)(ksm[0] + srow * 128 + (sc ^ kswz_w)) = ka;
  *(float4*)(ksm[1] + srow * 128 + (sc ^ kswz_w)) = kb2;
  *(float4*)(vsm[0] + srow * 128 + (sc ^ vswz_w)) = va;
  *(float4*)(vsm[1] + srow * 128 + (sc ^ vswz_w)) = vb2;
  __syncthreads();

  const int kswz = (lrow & 7) << 4;
  const float scale = 0.03608439182435161f; // 768^-0.5
  const bool useb = (kv0b <= q0w + 15);

  f32x4 S0[4];
#pragma unroll
  for (int cf = 0; cf < 4; ++cf) S0[cf] = (f32x4){0.f, 0.f, 0.f, 0.f};
#pragma unroll
  for (int cf = 0; cf < 4; ++cf) {
    const char* kp = ksm[0] + (cf * 16 + lrow) * 128;
#pragma unroll
    for (int s = 0; s < 2; ++s) {
      bf16x8 kf = *(const bf16x8*)(kp + ((s * 64 + lg * 16) ^ kswz));
      S0[cf] = __builtin_amdgcn_mfma_f32_16x16x32_bf16(kf, qf[s], S0[cf], 0, 0, 0);
    }
  }
  float tmx = -INFINITY;
  {
    const bool msk = (kv0a + 63 > q0w); // mask iff max col can exceed MIN row
#pragma unroll
    for (int cf = 0; cf < 4; ++cf)
#pragma unroll
      for (int r = 0; r < 4; ++r) {
        float vv = S0[cf][r] * scale;
        if (msk) {
          int kvi = kv0a + cf * 16 + lg * 4 + r;
          vv = (kvi > qrow) ? -INFINITY : vv;
        }
        S0[cf][r] = vv;
        tmx = fmaxf(tmx, vv);
      }
  }
  f32x4 S1[4];
  if (useb) {
#pragma unroll
    for (int cf = 0; cf < 4; ++cf) S1[cf] = (f32x4){0.f, 0.f, 0.f, 0.f};
#pragma unroll
    for (int cf = 0; cf < 4; ++cf) {
      const char* kp = ksm[1] + (cf * 16 + lrow) * 128;
#pragma unroll
      for (int s = 0; s < 2; ++s) {
        bf16x8 kf = *(const bf16x8*)(kp + ((s * 64 + lg * 16) ^ kswz));
        S1[cf] = __builtin_amdgcn_mfma_f32_16x16x32_bf16(kf, qf[s], S1[cf], 0, 0, 0);
      }
    }
    const bool msk = (kv0b + 63 > q0w); // mask iff max col can exceed MIN row
#pragma unroll
    for (int cf = 0; cf < 4; ++cf)
#pragma unroll
      for (int r = 0; r < 4; ++r) {
        float vv = S1[cf][r] * scale;
        if (msk) {
          int kvi = kv0b + cf * 16 + lg * 4 + r;
          vv = (kvi > qrow) ? -INFINITY : vv;
        }
        S1[cf][r] = vv;
        tmx = fmaxf(tmx, vv);
      }
  }
  tmx = fmaxf(tmx, __shfl_xor(tmx, 16));
  tmx = fmaxf(tmx, __shfl_xor(tmx, 32)); // joint row max

  float lsl = 0.f;
  f32x4 o[4];
#pragma unroll
  for (int hf = 0; hf < 4; ++hf) o[hf] = (f32x4){0.f, 0.f, 0.f, 0.f};
  const int rswz = (lrow & 3) << 5;

  {
    float p[4][4];
#pragma unroll
    for (int cf = 0; cf < 4; ++cf)
#pragma unroll
      for (int r = 0; r < 4; ++r) {
        float pe = __expf(S0[cf][r] - tmx);
        p[cf][r] = pe;
        lsl += pe;
      }
    union { unsigned u[4]; bf16x8 v; } pbu[2];
#pragma unroll
    for (int s = 0; s < 2; ++s) {
      pbu[s].u[0] = pack2bf(p[2 * s][0], p[2 * s][1]);
      pbu[s].u[1] = pack2bf(p[2 * s][2], p[2 * s][3]);
      pbu[s].u[2] = pack2bf(p[2 * s + 1][0], p[2 * s + 1][1]);
      pbu[s].u[3] = pack2bf(p[2 * s + 1][2], p[2 * s + 1][3]);
    }
#pragma unroll
    for (int s = 0; s < 2; ++s)
#pragma unroll
      for (int hf = 0; hf < 4; ++hf) {
        int r = hf * 16 + lrow;
        int a1 = r * 128 + ((s * 64 + lg * 8) ^ rswz);
        u32x2 lo = *(const u32x2*)(vsm[0] + a1);
        u32x2 hi = *(const u32x2*)(vsm[0] + (a1 ^ 32));
        union { unsigned u[4]; bf16x8 v; } vfu;
        vfu.u[0] = lo.x; vfu.u[1] = lo.y; vfu.u[2] = hi.x; vfu.u[3] = hi.y;
        o[hf] = __builtin_amdgcn_mfma_f32_16x16x32_bf16(vfu.v, pbu[s].v, o[hf], 0, 0, 0);
      }
  }
  if (useb) {
    float p[4][4];
#pragma unroll
    for (int cf = 0; cf < 4; ++cf)
#pragma unroll
      for (int r = 0; r < 4; ++r) {
        float pe = __expf(S1[cf][r] - tmx);
        p[cf][r] = pe;
        lsl += pe;
      }
    union { unsigned u[4]; bf16x8 v; } pbu[2];
#pragma unroll
    for (int s = 0; s < 2; ++s) {
      pbu[s].u[0] = pack2bf(p[2 * s][0], p[2 * s][1]);
      pbu[s].u[1] = pack2bf(p[2 * s][2], p[2 * s][3]);
      pbu[s].u[2] = pack2bf(p[2 * s + 1][0], p[2 * s + 1][1]);
      pbu[s].u[3] = pack2bf(p[2 * s + 1][2], p[2 * s + 1][3]);
    }
#pragma unroll
    for (int s = 0; s < 2; ++s)
#pragma unroll
      for (int hf = 0; hf < 4; ++hf) {
        int r = hf * 16 + lrow;
        int a1 = r * 128 + ((s * 64 + lg * 8) ^ rswz);
        u32x2 lo = *(const u32x2*)(vsm[1] + a1);
        u32x2 hi = *(const u32x2*)(vsm[1] + (a1 ^ 32));
        union { unsigned u[4]; bf16x8 v; } vfu;
        vfu.u[0] = lo.x; vfu.u[1] = lo.y; vfu.u[2] = hi.x; vfu.u[3] = hi.y;
        o[hf] = __builtin_amdgcn_mfma_f32_16x16x32_bf16(vfu.v, pbu[s].v, o[hf], 0, 0, 0);
      }
  }

  float ls = lsl;
  ls += __shfl_xor(ls, 16);
  ls += __shfl_xor(ls, 32);

  // split-major partial write, plane = b128
  size_t rowg = (size_t)b128 * NROWS + b * TB + qrow;
  unsigned short* pop = PO + rowg * 64 + lg * 4;
#pragma unroll
  for (int hf = 0; hf < 4; ++hf) {
    u32x2 pk;
    pk.x = pack2bf(o[hf][0], o[hf][1]);
    pk.y = pack2bf(o[hf][2], o[hf][3]);
    *(u32x2*)(pop + hf * 16) = pk;
  }
  if (lg == 0) {
    Mp[rowg] = tmx;
    Lp[rowg] = ls;
  }
}

// ---------------- kernel 2b: combine splits, 32 threads/row ------------------
__global__ void attn_reduce_kernel(const unsigned short* __restrict__ PO,
                                   const float* __restrict__ Mp,
                                   const float* __restrict__ Lp,
                                   float* __restrict__ out) {
  int id = blockIdx.x * 256 + threadIdx.x;
  if (id >= NROWS * 32) return;
  int row = id >> 5, h0 = (id & 31) * 2;
  int t = row & (TB - 1);
  int ns = (t >> 7) + 1; // 128-wide splits for this row
  float M = -INFINITY;
#pragma unroll 4
  for (int s = 0; s < ns; ++s) M = fmaxf(M, Mp[(size_t)s * NROWS + row]);
  float L = 0.f, a0 = 0.f, a1 = 0.f;
#pragma unroll 4
  for (int s = 0; s < ns; ++s) {
    float w = __expf(Mp[(size_t)s * NROWS + row] - M);
    L += Lp[(size_t)s * NROWS + row] * w;
    unsigned pv = *(const unsigned*)(PO + ((size_t)s * NROWS + row) * 64 + h0);
    a0 += bf2f((unsigned short)(pv & 0xffff)) * w;
    a1 += bf2f((unsigned short)(pv >> 16)) * w;
  }
  float rL = 1.f / L;
  f32x2 r; r.x = a0 * rL; r.y = a1 * rL;
  *(f32x2*)(out + (size_t)row * 64 + h0) = r;
}

extern "C" void kernel_launch(void* const* d_in, const int* in_sizes, int n_in,
                              void* d_out, int out_size, void* d_ws, size_t ws_size,
                              hipStream_t stream) {
  const float* x  = (const float*)d_in[0];
  const float* Wq = (const float*)d_in[1];
  const float* Wk = (const float*)d_in[2];
  const float* Wv = (const float*)d_in[3];
  float* out = (float*)d_out;

  unsigned short* Wt = (unsigned short*)d_ws;
  unsigned short* qb = Wt + 192 * CB;
  unsigned short* kb = qb + (size_t)NROWS * 64;
  unsigned short* vT = kb + (size_t)NROWS * 64;
  char* scratch = (char*)(vT + (size_t)NROWS * 64);

  unsigned short* PO = (unsigned short*)scratch;                // 16*8192*128 B = 16.8 MB
  float* Mp = (float*)(scratch + (size_t)NSMAX * NROWS * 64 * 2);
  float* Lp = Mp + (size_t)NSMAX * NROWS;

  hipLaunchKernelGGL(cvt_w_kernel, dim3(12, 3), dim3(256), 0, stream,
                     Wq, Wk, Wv, Wt);
  hipLaunchKernelGGL(proj_direct_kernel, dim3(NROWS / 32), dim3(512), 0, stream,
                     x, Wt, qb, kb, vT);
  hipLaunchKernelGGL(attn_kernel, dim3(WGPB, NB), dim3(512), 0, stream,
                     qb, kb, vT, PO, Mp, Lp);
  hipLaunchKernelGGL(attn_reduce_kernel, dim3((NROWS * 32) / 256), dim3(256), 0, stream,
                     PO, Mp, Lp, out);
}

// Round 22
// 50.688 us; speedup vs baseline: 1.0338x; 1.0338x over previous
//
#include <hip/hip_runtime.h>
#include <math.h>

// B=4, T=2048, C=768, H=64
#define TB 2048
#define CB 768
#define NB 4
#define NROWS (NB * TB) // 8192
#define NSMAX 16        // max 128-wide KV splits per row
#define WGPB 136        // per-batch attn WGs: sum_{g=0..15} (g+1)

typedef __attribute__((ext_vector_type(8))) short bf16x8;
typedef __attribute__((ext_vector_type(4))) float f32x4;
typedef __attribute__((ext_vector_type(2))) float f32x2;
typedef __attribute__((ext_vector_type(2))) unsigned int u32x2;
typedef __attribute__((ext_vector_type(4))) unsigned int u32x4;

__device__ inline unsigned short f2bf(float f) {
  union { float f; unsigned u; } v; v.f = f;
  unsigned r = v.u + 0x7FFFu + ((v.u >> 16) & 1u);
  return (unsigned short)(r >> 16);
}
__device__ inline unsigned pack2bf(float a, float b) {
  return (unsigned)f2bf(a) | ((unsigned)f2bf(b) << 16);
}
__device__ inline float bf2f(unsigned short u) {
  union { unsigned u; float f; } v; v.u = (unsigned)u << 16; return v.f;
}

// ---------------- kernel 0: weights fp32 [C][64] x3 -> Wt bf16 [192][768] ----
__global__ void cvt_w_kernel(const float* __restrict__ Wq, const float* __restrict__ Wk,
                             const float* __restrict__ Wv, unsigned short* __restrict__ Wt) {
  __shared__ float tw[64][65];
  const float* W = (blockIdx.y == 0) ? Wq : (blockIdx.y == 1) ? Wk : Wv;
  const int c0 = blockIdx.x * 64;
  const int row = threadIdx.x >> 2, seg = threadIdx.x & 3;
#pragma unroll
  for (int i = 0; i < 4; ++i) {
    float4 f = *(const float4*)(W + (size_t)(c0 + row) * 64 + seg * 16 + i * 4);
    tw[row][seg * 16 + i * 4 + 0] = f.x;
    tw[row][seg * 16 + i * 4 + 1] = f.y;
    tw[row][seg * 16 + i * 4 + 2] = f.z;
    tw[row][seg * 16 + i * 4 + 3] = f.w;
  }
  __syncthreads();
  const int j = threadIdx.x >> 2, cq = threadIdx.x & 3;
  unsigned short* dst = Wt + (size_t)(blockIdx.y * 64 + j) * CB + c0 + cq * 16;
  u32x4 ua, ub;
#pragma unroll
  for (int i = 0; i < 4; ++i) ua[i] = pack2bf(tw[cq * 16 + 2 * i][j], tw[cq * 16 + 2 * i + 1][j]);
#pragma unroll
  for (int i = 0; i < 4; ++i) ub[i] = pack2bf(tw[cq * 16 + 8 + 2 * i][j], tw[cq * 16 + 9 + 2 * i][j]);
  *(u32x4*)dst = ua;
  *(u32x4*)(dst + 8) = ub;
}

// ---------------- kernel 1: QKV projection, FULL-K, 16-row M-tiles -----------
__launch_bounds__(256)
__global__ void proj_direct_kernel(const float* __restrict__ x,
                                   const unsigned short* __restrict__ Wt,
                                   unsigned short* __restrict__ q,
                                   unsigned short* __restrict__ k,
                                   unsigned short* __restrict__ vT) {
  __shared__ __align__(16) unsigned short xs[16 * 64];
  __shared__ float tr[64][17];
  const int tid = threadIdx.x;
  const int wv = tid >> 6;
  const int l = tid & 63;
  const int lrow = l & 15, lg = l >> 4;
  const int m0 = blockIdx.x * 16;
  const int srow = tid >> 4;
  const int sq = tid & 15;
  const float* xp = x + (size_t)(m0 + srow) * CB + sq * 4;
  const int swz = (srow & 7) << 4;

  f32x4 acc[3];
#pragma unroll
  for (int n = 0; n < 3; ++n) acc[n] = (f32x4){0.f, 0.f, 0.f, 0.f};

  float4 f = *(const float4*)xp;
  for (int k0 = 0; k0 < CB; k0 += 64) {
    {
      u32x2 c;
      c.x = pack2bf(f.x, f.y);
      c.y = pack2bf(f.z, f.w);
      *(u32x2*)((char*)xs + srow * 128 + ((sq * 8) ^ swz)) = c;
    }
    if (k0 + 64 < CB) f = *(const float4*)(xp + k0 + 64);
    __syncthreads();

#pragma unroll
    for (int s = 0; s < 2; ++s) {
      bf16x8 af = *(const bf16x8*)((const char*)xs + lrow * 128 +
                                   ((s * 64 + lg * 16) ^ ((lrow & 7) << 4)));
#pragma unroll
      for (int nf = 0; nf < 3; ++nf) {
        int col = wv * 48 + nf * 16 + lrow;
        bf16x8 bfr = *(const bf16x8*)(Wt + (size_t)col * CB + k0 + s * 32 + lg * 8);
        acc[nf] = __builtin_amdgcn_mfma_f32_16x16x32_bf16(af, bfr, acc[nf], 0, 0, 0);
      }
    }
    __syncthreads();
  }

#pragma unroll
  for (int nf = 0; nf < 3; ++nf) {
    int j = wv * 48 + nf * 16 + lrow;
#pragma unroll
    for (int r = 0; r < 4; ++r) {
      int grow = m0 + lg * 4 + r;
      if (j < 64)       q[(size_t)grow * 64 + j] = f2bf(acc[nf][r]);
      else if (j < 128) k[(size_t)grow * 64 + (j - 64)] = f2bf(acc[nf][r]);
      else              tr[j - 128][lg * 4 + r] = acc[nf][r];
    }
  }
  __syncthreads();
  {
    const int b = m0 >> 11, t0 = m0 & (TB - 1);
    const int h = tid >> 2, tq = tid & 3;
    u32x2 pk;
    pk.x = pack2bf(tr[h][tq * 4 + 0], tr[h][tq * 4 + 1]);
    pk.y = pack2bf(tr[h][tq * 4 + 2], tr[h][tq * 4 + 3]);
    *(u32x2*)(vT + ((size_t)(b * 64 + h)) * TB + t0 + tq * 4) = pk;
  }
}

// ---------------- kernel 2: causal attention, 8 Q-tiles x 128-wide KV --------
// grid (WGPB, B), block 512 (8 waves). WG w -> (g, b128), b128 in [0, g].
__launch_bounds__(512)
__global__ void attn_kernel(const unsigned short* __restrict__ q,
                            const unsigned short* __restrict__ k,
                            const unsigned short* __restrict__ vT,
                            unsigned short* __restrict__ PO, float* __restrict__ Mp,
                            float* __restrict__ Lp) {
  __shared__ __align__(16) char ksm[2][8192]; // K sub-tiles, swz (r&7)<<4
  __shared__ __align__(16) char vsm[2][8192]; // V sub-tiles, swz (r&3)<<5
  const int tid = threadIdx.x;
  const int wid = tid >> 6, l = tid & 63;
  const int lrow = l & 15, lg = l >> 4;
  const int b = blockIdx.y;
  const int w = blockIdx.x;

  int g = (int)((sqrtf((float)(8 * w + 1)) - 1.f) * 0.5f);
  while ((g + 1) * (g + 2) / 2 <= w) ++g;
  while (g * (g + 1) / 2 > w) --g;
  const int b128 = w - g * (g + 1) / 2;
  const int kv0a = b128 * 128, kv0b = kv0a + 64;
  const int t = 8 * g + wid;
  const int q0w = t * 16;
  const int qrow = q0w + lrow;

  const unsigned short* qb = q + (size_t)b * TB * 64;
  const char* kbb = (const char*)(k + (size_t)b * TB * 64);
  const unsigned short* vb = vT + (size_t)b * 64 * TB;

  const int srow = tid >> 3;
  const int sc = (tid & 7) * 16;
  const int kswz_w = (srow & 7) << 4;
  const int vswz_w = (srow & 3) << 5;
  float4 ka = *(const float4*)(kbb + (size_t)kv0a * 128 + tid * 16);
  float4 kb2 = *(const float4*)(kbb + (size_t)kv0b * 128 + tid * 16);
  float4 va = *(const float4*)((const char*)(vb + (size_t)srow * TB + kv0a) + sc);
  float4 vb2 = *(const float4*)((const char*)(vb + (size_t)srow * TB + kv0b) + sc);

  bf16x8 qf[2];
#pragma unroll
  for (int s = 0; s < 2; ++s)
    qf[s] = *(const bf16x8*)(qb + (size_t)qrow * 64 + s * 32 + lg * 8);

  *(float4*)(ksm[0] + srow * 128 + (sc ^ kswz_w)) = ka;
  *(float4*)(ksm[1] + srow * 128 + (sc ^ kswz_w)) = kb2;
  *(float4*)(vsm[0] + srow * 128 + (sc ^ vswz_w)) = va;
  *(float4*)(vsm[1] + srow * 128 + (sc ^ vswz_w)) = vb2;
  __syncthreads();

  const int kswz = (lrow & 7) << 4;
  const float scale = 0.03608439182435161f; // 768^-0.5
  const bool useb = (kv0b <= q0w + 15);

  f32x4 S0[4];
#pragma unroll
  for (int cf = 0; cf < 4; ++cf) S0[cf] = (f32x4){0.f, 0.f, 0.f, 0.f};
#pragma unroll
  for (int cf = 0; cf < 4; ++cf) {
    const char* kp = ksm[0] + (cf * 16 + lrow) * 128;
#pragma unroll
    for (int s = 0; s < 2; ++s) {
      bf16x8 kf = *(const bf16x8*)(kp + ((s * 64 + lg * 16) ^ kswz));
      S0[cf] = __builtin_amdgcn_mfma_f32_16x16x32_bf16(kf, qf[s], S0[cf], 0, 0, 0);
    }
  }
  float tmx = -INFINITY;
  {
    const bool msk = (kv0a + 63 > q0w); // mask iff max col can exceed MIN row
#pragma unroll
    for (int cf = 0; cf < 4; ++cf)
#pragma unroll
      for (int r = 0; r < 4; ++r) {
        float vv = S0[cf][r] * scale;
        if (msk) {
          int kvi = kv0a + cf * 16 + lg * 4 + r;
          vv = (kvi > qrow) ? -INFINITY : vv;
        }
        S0[cf][r] = vv;
        tmx = fmaxf(tmx, vv);
      }
  }
  f32x4 S1[4];
  if (useb) {
#pragma unroll
    for (int cf = 0; cf < 4; ++cf) S1[cf] = (f32x4){0.f, 0.f, 0.f, 0.f};
#pragma unroll
    for (int cf = 0; cf < 4; ++cf) {
      const char* kp = ksm[1] + (cf * 16 + lrow) * 128;
#pragma unroll
      for (int s = 0; s < 2; ++s) {
        bf16x8 kf = *(const bf16x8*)(kp + ((s * 64 + lg * 16) ^ kswz));
        S1[cf] = __builtin_amdgcn_mfma_f32_16x16x32_bf16(kf, qf[s], S1[cf], 0, 0, 0);
      }
    }
    const bool msk = (kv0b + 63 > q0w); // mask iff max col can exceed MIN row
#pragma unroll
    for (int cf = 0; cf < 4; ++cf)
#pragma unroll
      for (int r = 0; r < 4; ++r) {
        float vv = S1[cf][r] * scale;
        if (msk) {
          int kvi = kv0b + cf * 16 + lg * 4 + r;
          vv = (kvi > qrow) ? -INFINITY : vv;
        }
        S1[cf][r] = vv;
        tmx = fmaxf(tmx, vv);
      }
  }
  tmx = fmaxf(tmx, __shfl_xor(tmx, 16));
  tmx = fmaxf(tmx, __shfl_xor(tmx, 32)); // joint row max

  float lsl = 0.f;
  f32x4 o[4];
#pragma unroll
  for (int hf = 0; hf < 4; ++hf) o[hf] = (f32x4){0.f, 0.f, 0.f, 0.f};
  const int rswz = (lrow & 3) << 5;

  {
    float p[4][4];
#pragma unroll
    for (int cf = 0; cf < 4; ++cf)
#pragma unroll
      for (int r = 0; r < 4; ++r) {
        float pe = __expf(S0[cf][r] - tmx);
        p[cf][r] = pe;
        lsl += pe;
      }
    union { unsigned u[4]; bf16x8 v; } pbu[2];
#pragma unroll
    for (int s = 0; s < 2; ++s) {
      pbu[s].u[0] = pack2bf(p[2 * s][0], p[2 * s][1]);
      pbu[s].u[1] = pack2bf(p[2 * s][2], p[2 * s][3]);
      pbu[s].u[2] = pack2bf(p[2 * s + 1][0], p[2 * s + 1][1]);
      pbu[s].u[3] = pack2bf(p[2 * s + 1][2], p[2 * s + 1][3]);
    }
#pragma unroll
    for (int s = 0; s < 2; ++s)
#pragma unroll
      for (int hf = 0; hf < 4; ++hf) {
        int r = hf * 16 + lrow;
        int a1 = r * 128 + ((s * 64 + lg * 8) ^ rswz);
        u32x2 lo = *(const u32x2*)(vsm[0] + a1);
        u32x2 hi = *(const u32x2*)(vsm[0] + (a1 ^ 32));
        union { unsigned u[4]; bf16x8 v; } vfu;
        vfu.u[0] = lo.x; vfu.u[1] = lo.y; vfu.u[2] = hi.x; vfu.u[3] = hi.y;
        o[hf] = __builtin_amdgcn_mfma_f32_16x16x32_bf16(vfu.v, pbu[s].v, o[hf], 0, 0, 0);
      }
  }
  if (useb) {
    float p[4][4];
#pragma unroll
    for (int cf = 0; cf < 4; ++cf)
#pragma unroll
      for (int r = 0; r < 4; ++r) {
        float pe = __expf(S1[cf][r] - tmx);
        p[cf][r] = pe;
        lsl += pe;
      }
    union { unsigned u[4]; bf16x8 v; } pbu[2];
#pragma unroll
    for (int s = 0; s < 2; ++s) {
      pbu[s].u[0] = pack2bf(p[2 * s][0], p[2 * s][1]);
      pbu[s].u[1] = pack2bf(p[2 * s][2], p[2 * s][3]);
      pbu[s].u[2] = pack2bf(p[2 * s + 1][0], p[2 * s + 1][1]);
      pbu[s].u[3] = pack2bf(p[2 * s + 1][2], p[2 * s + 1][3]);
    }
#pragma unroll
    for (int s = 0; s < 2; ++s)
#pragma unroll
      for (int hf = 0; hf < 4; ++hf) {
        int r = hf * 16 + lrow;
        int a1 = r * 128 + ((s * 64 + lg * 8) ^ rswz);
        u32x2 lo = *(const u32x2*)(vsm[1] + a1);
        u32x2 hi = *(const u32x2*)(vsm[1] + (a1 ^ 32));
        union { unsigned u[4]; bf16x8 v; } vfu;
        vfu.u[0] = lo.x; vfu.u[1] = lo.y; vfu.u[2] = hi.x; vfu.u[3] = hi.y;
        o[hf] = __builtin_amdgcn_mfma_f32_16x16x32_bf16(vfu.v, pbu[s].v, o[hf], 0, 0, 0);
      }
  }

  float ls = lsl;
  ls += __shfl_xor(ls, 16);
  ls += __shfl_xor(ls, 32);

  // split-major partial write, plane = b128
  size_t rowg = (size_t)b128 * NROWS + b * TB + qrow;
  unsigned short* pop = PO + rowg * 64 + lg * 4;
#pragma unroll
  for (int hf = 0; hf < 4; ++hf) {
    u32x2 pk;
    pk.x = pack2bf(o[hf][0], o[hf][1]);
    pk.y = pack2bf(o[hf][2], o[hf][3]);
    *(u32x2*)(pop + hf * 16) = pk;
  }
  if (lg == 0) {
    Mp[rowg] = tmx;
    Lp[rowg] = ls;
  }
}

// ---------------- kernel 2b: combine splits, 32 threads/row ------------------
__global__ void attn_reduce_kernel(const unsigned short* __restrict__ PO,
                                   const float* __restrict__ Mp,
                                   const float* __restrict__ Lp,
                                   float* __restrict__ out) {
  int id = blockIdx.x * 256 + threadIdx.x;
  if (id >= NROWS * 32) return;
  int row = id >> 5, h0 = (id & 31) * 2;
  int t = row & (TB - 1);
  int ns = (t >> 7) + 1; // 128-wide splits for this row
  float M = -INFINITY;
#pragma unroll 4
  for (int s = 0; s < ns; ++s) M = fmaxf(M, Mp[(size_t)s * NROWS + row]);
  float L = 0.f, a0 = 0.f, a1 = 0.f;
#pragma unroll 4
  for (int s = 0; s < ns; ++s) {
    float w = __expf(Mp[(size_t)s * NROWS + row] - M);
    L += Lp[(size_t)s * NROWS + row] * w;
    unsigned pv = *(const unsigned*)(PO + ((size_t)s * NROWS + row) * 64 + h0);
    a0 += bf2f((unsigned short)(pv & 0xffff)) * w;
    a1 += bf2f((unsigned short)(pv >> 16)) * w;
  }
  float rL = 1.f / L;
  f32x2 r; r.x = a0 * rL; r.y = a1 * rL;
  *(f32x2*)(out + (size_t)row * 64 + h0) = r;
}

extern "C" void kernel_launch(void* const* d_in, const int* in_sizes, int n_in,
                              void* d_out, int out_size, void* d_ws, size_t ws_size,
                              hipStream_t stream) {
  const float* x  = (const float*)d_in[0];
  const float* Wq = (const float*)d_in[1];
  const float* Wk = (const float*)d_in[2];
  const float* Wv = (const float*)d_in[3];
  float* out = (float*)d_out;

  unsigned short* Wt = (unsigned short*)d_ws;
  unsigned short* qb = Wt + 192 * CB;
  unsigned short* kb = qb + (size_t)NROWS * 64;
  unsigned short* vT = kb + (size_t)NROWS * 64;
  char* scratch = (char*)(vT + (size_t)NROWS * 64);

  unsigned short* PO = (unsigned short*)scratch;                // 16*8192*128 B = 16.8 MB
  float* Mp = (float*)(scratch + (size_t)NSMAX * NROWS * 64 * 2);
  float* Lp = Mp + (size_t)NSMAX * NROWS;

  hipLaunchKernelGGL(cvt_w_kernel, dim3(12, 3), dim3(256), 0, stream,
                     Wq, Wk, Wv, Wt);
  hipLaunchKernelGGL(proj_direct_kernel, dim3(NROWS / 16), dim3(256), 0, stream,
                     x, Wt, qb, kb, vT);
  hipLaunchKernelGGL(attn_kernel, dim3(WGPB, NB), dim3(512), 0, stream,
                     qb, kb, vT, PO, Mp, Lp);
  hipLaunchKernelGGL(attn_reduce_kernel, dim3((NROWS * 32) / 256), dim3(256), 0, stream,
                     PO, Mp, Lp, out);
}